// Round 4
// baseline (58.069 us; speedup 1.0000x reference)
//
#include <hip/hip_runtime.h>

#define B_    16
#define L_    512
#define N_    64
#define D_    256
#define T_    16                 // outputs per thread (t-tile height)
#define NT    (L_ / T_)          // 32 tiles per batch
#define KROWS (L_ + T_)          // 528 rows: tau = row-16, rows 0..15 zero
#define RING  8                  // prefetch depth (covers ~280 cyc > L2 ~200)
#define GUARD RING               // guard rows below Kpad row 0

// ---------------------------------------------------------------------------
// Kernel A: Kpad[row][d] = sum_n Re( (P[n,d]) * (dt*B[n]) * a[n]^tau ), tau=row-16
// ---------------------------------------------------------------------------
__global__ __launch_bounds__(256)
void build_K(const float* __restrict__ Lre_p, const float* __restrict__ Lim_p,
             const float* __restrict__ Bre_p, const float* __restrict__ Bim_p,
             const float* __restrict__ Pre_p, const float* __restrict__ Pim_p,
             const float* __restrict__ logdt_p,
             float* __restrict__ Kpad)   // points at row 0 (after guard)
{
    __shared__ float U[N_], V[N_];
    const int row = blockIdx.x;          // 0..KROWS-1
    const int tau = row - T_;
    const int d   = threadIdx.x;

    if (tau < 0) {                        // uniform per block
        Kpad[row * D_ + d] = 0.f;
        return;
    }

    const float dt = expf(logdt_p[0]);
    if (d < N_) {
        const float Lre = Lre_p[d], Lim = Lim_p[d];
        const float eL  = expf(Lre);
        const float wre = -eL * cosf(Lim);
        const float wim = -eL * sinf(Lim);
        const float ft  = (float)tau;
        const float er  = expf(ft * dt * wre);      // |a|^tau
        float sn, cs;
        sincosf(ft * dt * wim, &sn, &cs);
        const float Ar = er * cs, Ai = er * sn;     // a^tau
        const float Bdre = dt * Bre_p[d], Bdim = dt * Bim_p[d];
        U[d] = Bdre * Ar - Bdim * Ai;
        V[d] = Bdim * Ar + Bdre * Ai;
    }
    __syncthreads();

    float acc = 0.f;
    #pragma unroll 8
    for (int n = 0; n < N_; ++n)
        acc = fmaf(Pre_p[n * D_ + d], U[n],
              fmaf(-Pim_p[n * D_ + d], V[n], acc));
    Kpad[row * D_ + d] = acc;
}

// ---------------------------------------------------------------------------
// Kernel B: causal FIR, 512 threads = 2 history-halves x 256 channels.
// Each half runs a rolling-16 K window over its chunk range; LDS-combine.
// ---------------------------------------------------------------------------

// one 16-step chunk starting at s0.  TAILMASK: mask u prefetch index (&511)
#define STEP16(S0, TAILMASK)                                                 \
    {                                                                        \
        const int s0_ = (S0);                                                \
        _Pragma("unroll")                                                    \
        for (int m = 0; m < 16; ++m) {                                       \
            const float uv = ur[m & (RING - 1)];                             \
            const float kv = kr[m & (RING - 1)];                             \
            acc[0] = fmaf(kv, uv, acc[0]);                                   \
            _Pragma("unroll")                                                \
            for (int j = 1; j < 16; ++j)                                     \
                acc[j] = fmaf(W[(j - m) & 15], uv, acc[j]);                  \
            W[(16 - m) & 15] = kv;                                           \
            kr[m & (RING - 1)] = Kb[(r0 - (s0_ + m) - RING) * D_];           \
            int spf = s0_ + m + RING;                                        \
            if (TAILMASK) spf &= (L_ - 1);                                   \
            ur[m & (RING - 1)] = ub[spf * D_];                               \
        }                                                                    \
    }

__global__ __launch_bounds__(512, 4)
void conv_fir(const float* __restrict__ u, const float* __restrict__ Kpad,
              float* __restrict__ y)      // Kpad points at row 0 (after guard)
{
    __shared__ float part[D_][T_ + 1];    // 17.4 KB

    const int g  = blockIdx.x;                   // 0..511
    const int b  = g & (B_ - 1);
    const int kk = g >> 4;                       // 0..31
    const int k  = (kk < 16) ? kk : (47 - kk);   // pair heavy+light per CU
    const int h  = threadIdx.x >> 8;             // history half 0/1
    const int d  = threadIdx.x & (D_ - 1);

    const int C  = k + 1;                        // total 16-step chunks
    const int c0 = (h * C) >> 1;
    const int c1 = ((h + 1) * C) >> 1;
    const int sA = c0 * T_;                      // this half's s range
    const int sB = c1 * T_;
    const int r0 = T_ * k + T_;                  // K row entering at s=0

    const float* ub = u + ((size_t)b * L_) * D_ + d;          // + s*D_
    const float* Kb = Kpad + d;                               // + row*D_
    float*       yb = y + ((size_t)b * L_ + k * T_) * D_ + d; // + j*D_

    // rolling window + prefetch rings (prologue rows all >= 9, in-bounds)
    float W[16];
    W[0] = 0.f;
    #pragma unroll
    for (int j = 1; j < 16; ++j) W[j] = Kb[(r0 - sA + j) * D_];
    float kr[RING], ur[RING];
    #pragma unroll
    for (int p = 0; p < RING; ++p) {
        kr[p] = Kb[(r0 - sA - p) * D_];          // rows for s = sA..sA+7
        ur[p] = ub[(sA + p) * D_];               // sA+7 <= 503, in-bounds
    }
    float acc[16];
    #pragma unroll
    for (int j = 0; j < 16; ++j) acc[j] = 0.f;

    // main chunks: u prefetch s+8 <= sB-9 < 512, affine address
    for (int s0 = sA; s0 < sB - 16; s0 += 16)
        STEP16(s0, 0)
    // tail chunk: u prefetch may reach >= 512 -> wrap (values never consumed)
    if (sB > sA)
        STEP16(sB - 16, 1)

    if (h == 1) {
        #pragma unroll
        for (int j = 0; j < 16; ++j) part[d][j] = acc[j];
    }
    __syncthreads();
    if (h == 0) {
        #pragma unroll
        for (int j = 0; j < 16; ++j)
            yb[j * D_] = acc[j] + part[d][j];
    }
}

extern "C" void kernel_launch(void* const* d_in, const int* in_sizes, int n_in,
                              void* d_out, int out_size, void* d_ws, size_t ws_size,
                              hipStream_t stream) {
    const float* u     = (const float*)d_in[0];
    const float* Lre   = (const float*)d_in[1];
    const float* Lim   = (const float*)d_in[2];
    const float* Bre   = (const float*)d_in[3];
    const float* Bim   = (const float*)d_in[4];
    const float* Pre   = (const float*)d_in[5];
    const float* Pim   = (const float*)d_in[6];
    const float* logdt = (const float*)d_in[7];
    float* y = (float*)d_out;

    float* Kpad0 = (float*)d_ws;             // GUARD rows live here
    float* Kpad  = Kpad0 + GUARD * D_;       // row 0 of the real table

    build_K<<<KROWS, 256, 0, stream>>>(Lre, Lim, Bre, Bim, Pre, Pim, logdt, Kpad);
    conv_fir<<<B_ * NT, 512, 0, stream>>>(u, Kpad, y);
}